// Round 9
// baseline (305.446 us; speedup 1.0000x reference)
//
#include <hip/hip_runtime.h>

typedef unsigned short u16;
typedef unsigned int u32;
typedef __attribute__((ext_vector_type(8))) short bf16x8;
typedef __attribute__((ext_vector_type(4))) float f32x4;
typedef __attribute__((ext_vector_type(4))) u16 u16x4;
typedef __attribute__((ext_vector_type(2))) u32 u32x2;

#define DIM 128
// Y row (2816 B): per type t in 0..3 at t*384:
//   [0,128):   q fp8 (feat = byte offset)
//   [128,384): v bf16 (feat*2)
// 1536 + t*256: k bf16 ; 2560: s bf16
#define ROWB 2816
#define QV_SPAN 384
#define K_OFF 1536
#define S_OFF 2560
#define AS1C(p) ((const __attribute__((address_space(1))) void*)(p))
#define AS3P(p) ((__attribute__((address_space(3))) void*)(p))

__device__ __forceinline__ u32 f2bf(float f){
  u32 x = __float_as_uint(f);
  return (x + 0x7fffu + ((x >> 16) & 1u)) >> 16;
}
__device__ __forceinline__ float bf2f(u16 u){
  return __uint_as_float(((u32)u) << 16);
}
__device__ __forceinline__ bf16x8 pack_bf16x8(f32x4 lo, f32x4 hi){
  union { u32 w[4]; bf16x8 v; } u;
  u.w[0] = f2bf(lo.x) | (f2bf(lo.y) << 16);
  u.w[1] = f2bf(lo.z) | (f2bf(lo.w) << 16);
  u.w[2] = f2bf(hi.x) | (f2bf(hi.y) << 16);
  u.w[3] = f2bf(hi.z) | (f2bf(hi.w) << 16);
  return u.v;
}

// ------------- prep: hist + build W (bf16, transposed, concat) ---------------
// Wcat tiles (13 x 128 cols): nt<4: Wq[nt]; 4..7: Wv; 8..11: Wk; 12: mean Ws.
__global__ __launch_bounds__(256) void prep_kernel(
    const int* __restrict__ dst, int* __restrict__ cnt, int* __restrict__ rank,
    const float* __restrict__ Wk, const float* __restrict__ bk,
    const float* __restrict__ Wq, const float* __restrict__ bq,
    const float* __restrict__ Wv, const float* __restrict__ bv,
    const float* __restrict__ Ws, const float* __restrict__ bb,
    u16* __restrict__ WcatT, float* __restrict__ biascat,
    int T, int E){
  int id = blockIdx.x * 256 + threadIdx.x;
  if (id < E){
    rank[id] = atomicAdd(&cnt[dst[id]], 1);
    return;
  }
  id -= E;
  int total_w = (3 * T + 1) * DIM * DIM;
  if (id >= total_w) return;
  int kk = id & (DIM - 1);
  int c  = id >> 7;
  int nt = c >> 7;
  int j  = c & (DIM - 1);
  float wv, bvv;
  if (nt < T)        { wv = Wq[(nt*DIM + kk)*DIM + j];       bvv = bq[nt*DIM + j]; }
  else if (nt < 2*T) { wv = Wv[((nt-T)*DIM + kk)*DIM + j];   bvv = bv[(nt-T)*DIM + j]; }
  else if (nt < 3*T) { wv = Wk[((nt-2*T)*DIM + kk)*DIM + j]; bvv = bk[(nt-2*T)*DIM + j]; }
  else {
    float s = 0.f, sb = 0.f;
    for (int t = 0; t < T; ++t){ s += Ws[(t*DIM + kk)*DIM + j]; sb += bb[t*DIM + j]; }
    wv = s / (float)T; bvv = sb / (float)T;
  }
  WcatT[(size_t)c * DIM + kk] = (u16)f2bf(wv);
  if (kk == 0) biascat[c] = bvv;
}

// per-2048-chunk exclusive scan (offs chunk-local; bsum = chunk totals)
__global__ __launch_bounds__(256) void scan1_kernel(const int* __restrict__ cnt,
                                                    int* __restrict__ offs,
                                                    int* __restrict__ bsum, int n){
  __shared__ int wsum[4];
  const int tid = threadIdx.x;
  const int lane = tid & 63, wave = tid >> 6;
  const int base = blockIdx.x * 2048 + tid * 8;
  int v[8]; int tot = 0;
#pragma unroll
  for (int j = 0; j < 8; ++j){
    int idx = base + j;
    int val = (idx < n) ? cnt[idx] : 0;
    v[j] = val; tot += val;
  }
  int incl = tot;
#pragma unroll
  for (int d = 1; d < 64; d <<= 1){
    int u = __shfl_up(incl, d, 64);
    if (lane >= d) incl += u;
  }
  if (lane == 63) wsum[wave] = incl;
  __syncthreads();
  int wbase = 0;
#pragma unroll
  for (int w = 0; w < 4; ++w) if (w < wave) wbase += wsum[w];
  int excl = wbase + incl - tot;
  if (tid == 255) bsum[blockIdx.x] = wbase + incl;
#pragma unroll
  for (int j = 0; j < 8; ++j){
    int idx = base + j;
    if (idx < n) offs[idx] = excl;
    excl += v[j];
  }
}

// exclusive scan of chunk sums (nb <= 64)
__global__ __launch_bounds__(64) void scan2_kernel(const int* __restrict__ bsum,
                                                   int* __restrict__ boffs, int nb){
  int lane = threadIdx.x;
  int v = (lane < nb) ? bsum[lane] : 0;
  int incl = v;
#pragma unroll
  for (int d = 1; d < 64; d <<= 1){
    int u = __shfl_up(incl, d, 64);
    if (lane >= d) incl += u;
  }
  if (lane < nb) boffs[lane] = incl - v;
}

// ---------------- fused scatter + GEMM ---------------------------------------
// Blocks [0, nsc): scatter packed[] (no atomics: offs+boffs+rank).
// Blocks [nsc, ...): GEMM Y = x @ Wcat + bias; x read fp32, packed to bf16
// in-register (hides under the LDS-DMA drain). W-tile (32 KB) LDS, XOR
// swizzle, global_load_lds w16. XCD swizzle: groups of 8 blocks = 8 m-tiles.
// D mapping (A=W^T frag, B=x frag): col(=node)=lane&15, row(=feat)=quad*4+reg.
__global__ __launch_bounds__(256, 4) void gemm_scatter_kernel(
    const float* __restrict__ x, const u16* __restrict__ WcatT,
    const float* __restrict__ biascat, char* __restrict__ Y,
    const int* __restrict__ src, const int* __restrict__ dst,
    const int* __restrict__ et, const int* __restrict__ offs,
    const int* __restrict__ boffs, const int* __restrict__ rank,
    int* __restrict__ packed,
    int N, int E, int T, int NB, int mtiles, int nsc){
  __shared__ u16 wt[DIM * DIM];   // 32 KB
  int bid = blockIdx.x;
  if (bid < nsc){
    int e = bid * 256 + threadIdx.x;
    if (e < E){
      int d = dst[e];
      int pos = offs[d] + boffs[d >> 11] + rank[e];
      packed[pos] = (src[e] << 2) | (et[e] & 3);
    }
    return;
  }
  bid -= nsc;
  int body = NB * (mtiles & ~7);
  int mt, nt;
  if (bid < body){
    int g = bid >> 3, r = bid & 7;
    int a = g / NB;
    mt = a * 8 + r;
    nt = g - a * NB;
  } else {
    int z = bid - body;
    mt = (mtiles & ~7) + z / NB;
    nt = z % NB;
  }
  const int m0 = mt * 128;
  const int n0 = nt * 128;
  const int tid  = threadIdx.x;
  const int wave = tid >> 6;
  const int lane = tid & 63;
  const int l15  = lane & 15;
  const int quad = lane >> 4;
  const int wrow = wave * 32;

  // x rows (fp32, clamped for padded tail; garbage accs are never stored)
  int r0 = m0 + wrow + l15;      if (r0 > N - 1) r0 = N - 1;
  int r1 = m0 + wrow + 16 + l15; if (r1 > N - 1) r1 = N - 1;
  const float* xp0 = x + (size_t)r0 * DIM + quad * 8;
  const float* xp1 = x + (size_t)r1 * DIM + quad * 8;

  // issue x loads (independent of the LDS DMA)
  f32x4 xl[2][4][2];
#pragma unroll
  for (int ks = 0; ks < 4; ++ks){
    xl[0][ks][0] = *(const f32x4*)(xp0 + ks * 32);
    xl[0][ks][1] = *(const f32x4*)(xp0 + ks * 32 + 4);
    xl[1][ks][0] = *(const f32x4*)(xp1 + ks * 32);
    xl[1][ks][1] = *(const f32x4*)(xp1 + ks * 32 + 4);
  }

  // stage W tile, XOR swizzle: phys block p of row r holds logical p^(r&7)
#pragma unroll
  for (int it = 0; it < 8; ++it){
    int s  = it * 256 + tid;
    int r  = s >> 4;
    int p  = s & 15;
    int lb = p ^ (r & 7);
    int lbase = (it * 256 + wave * 64) * 8;
    __builtin_amdgcn_global_load_lds(AS1C(WcatT + (size_t)(n0 + r) * DIM + lb * 8),
                                     AS3P(wt + lbase), 16, 0, 0);
  }

  // pack x to bf16 (overlaps the DMA drain)
  bf16x8 bfr[2][4];
#pragma unroll
  for (int ks = 0; ks < 4; ++ks){
    bfr[0][ks] = pack_bf16x8(xl[0][ks][0], xl[0][ks][1]);
    bfr[1][ks] = pack_bf16x8(xl[1][ks][0], xl[1][ks][1]);
  }
  __syncthreads();

  f32x4 acc[2][8];
#pragma unroll
  for (int m = 0; m < 2; ++m)
#pragma unroll
    for (int f = 0; f < 8; ++f)
      acc[m][f] = (f32x4){0.f, 0.f, 0.f, 0.f};

#pragma unroll
  for (int ks = 0; ks < 4; ++ks){
    const int pb8 = (((ks * 4 + quad) ^ (l15 & 7)) * 8);
#pragma unroll
    for (int f = 0; f < 8; ++f){
      bf16x8 afr = *(const bf16x8*)&wt[(f * 16 + l15) * DIM + pb8];
      acc[0][f] = __builtin_amdgcn_mfma_f32_16x16x32_bf16(afr, bfr[0][ks], acc[0][f], 0, 0, 0);
      acc[1][f] = __builtin_amdgcn_mfma_f32_16x16x32_bf16(afr, bfr[1][ks], acc[1][f], 0, 0, 0);
    }
  }

  // epilogue by tile class: nt<T -> q fp8; [T,2T) -> v bf16; [2T,3T) -> k; 12 -> s
#pragma unroll
  for (int m = 0; m < 2; ++m){
    int node = m0 + wrow + m * 16 + l15;
    if (node >= N) continue;
    char* rb = Y + (size_t)node * ROWB;
#pragma unroll
    for (int f = 0; f < 8; ++f){
      int feat = f * 16 + quad * 4;
      f32x4 b4 = *(const f32x4*)&biascat[n0 + feat];
      f32x4 v  = acc[m][f];
      float a0 = v.x + b4.x, a1 = v.y + b4.y, a2 = v.z + b4.z, a3 = v.w + b4.w;
      if (nt < T){                       // q -> fp8
        u32 w = __builtin_amdgcn_cvt_pk_fp8_f32(a0, a1, 0, false);
        w = __builtin_amdgcn_cvt_pk_fp8_f32(a2, a3, w, true);
        *(u32*)(rb + nt * QV_SPAN + feat) = w;
      } else {
        u32 lo = f2bf(a0) | (f2bf(a1) << 16);
        u32 hi = f2bf(a2) | (f2bf(a3) << 16);
        u32x2 pk = {lo, hi};
        int boff;
        if (nt < 2*T)      boff = (nt - T) * QV_SPAN + 128 + feat * 2;  // v
        else if (nt < 3*T) boff = K_OFF + (nt - 2*T) * 256 + feat * 2;  // k
        else               boff = S_OFF + feat * 2;                     // s
        *(u32x2*)(rb + boff) = pk;
      }
    }
  }
}

// ---------------- aggregate + epilogue: 2 nodes per wave (32 lanes each) -----
__global__ __launch_bounds__(256) void agg_kernel(const char* __restrict__ Y,
                                                  const int* __restrict__ offs,
                                                  const int* __restrict__ boffs,
                                                  const int* __restrict__ packed,
                                                  float* __restrict__ out,
                                                  int N, int E, float invT){
  const int wave = threadIdx.x >> 6;
  const int lane = threadIdx.x & 63;
  const int half = lane >> 5;
  const int l32  = lane & 31;
  const int node = blockIdx.x * 8 + wave * 2 + half;
  const bool valid = node < N;
  const int nc = valid ? node : N - 1;

  const char* yr = Y + (size_t)nc * ROWB;

  f32x4 kf[4];
#pragma unroll
  for (int t = 0; t < 4; ++t){
    u16x4 kw = *(const u16x4*)(yr + K_OFF + t * 256 + l32 * 8);
    kf[t] = (f32x4){ bf2f(kw.x), bf2f(kw.y), bf2f(kw.z), bf2f(kw.w) };
  }
  u16x4 sw = *(const u16x4*)(yr + S_OFF + l32 * 8);

  int e0 = 0, e1 = 0;
  if (valid){
    e0 = offs[nc] + boffs[nc >> 11];
    e1 = (nc == N - 1) ? E : (offs[nc + 1] + boffs[(nc + 1) >> 11]);
  }

  f32x4 acc = {0.f, 0.f, 0.f, 0.f};
  int e = e0;
  for (; e + 8 <= e1; e += 8){
    int p[8];
#pragma unroll
    for (int j = 0; j < 8; ++j) p[j] = packed[e + j];
    u32 qw[8]; u16x4 vw[8];
#pragma unroll
    for (int j = 0; j < 8; ++j){
      const char* sb = Y + (size_t)(p[j] >> 2) * ROWB + (p[j] & 3) * QV_SPAN;
      qw[j] = *(const u32*)(sb + l32 * 4);
      vw[j] = *(const u16x4*)(sb + 128 + l32 * 8);
    }
#pragma unroll
    for (int j = 0; j < 8; ++j){
      int t = p[j] & 3;
      f32x4 kt = (t == 0) ? kf[0] : (t == 1) ? kf[1] : (t == 2) ? kf[2] : kf[3];
      acc.x += bf2f(vw[j].x) * __builtin_amdgcn_rcpf(1.f + __expf(-(kt.x + __builtin_amdgcn_cvt_f32_fp8(qw[j], 0))));
      acc.y += bf2f(vw[j].y) * __builtin_amdgcn_rcpf(1.f + __expf(-(kt.y + __builtin_amdgcn_cvt_f32_fp8(qw[j], 1))));
      acc.z += bf2f(vw[j].z) * __builtin_amdgcn_rcpf(1.f + __expf(-(kt.z + __builtin_amdgcn_cvt_f32_fp8(qw[j], 2))));
      acc.w += bf2f(vw[j].w) * __builtin_amdgcn_rcpf(1.f + __expf(-(kt.w + __builtin_amdgcn_cvt_f32_fp8(qw[j], 3))));
    }
  }
  for (; e < e1; ++e){
    int p = packed[e];
    int t = p & 3;
    const char* sb = Y + (size_t)(p >> 2) * ROWB + t * QV_SPAN;
    u32 qw = *(const u32*)(sb + l32 * 4);
    u16x4 vw = *(const u16x4*)(sb + 128 + l32 * 8);
    f32x4 kt = (t == 0) ? kf[0] : (t == 1) ? kf[1] : (t == 2) ? kf[2] : kf[3];
    acc.x += bf2f(vw.x) * __builtin_amdgcn_rcpf(1.f + __expf(-(kt.x + __builtin_amdgcn_cvt_f32_fp8(qw, 0))));
    acc.y += bf2f(vw.y) * __builtin_amdgcn_rcpf(1.f + __expf(-(kt.y + __builtin_amdgcn_cvt_f32_fp8(qw, 1))));
    acc.z += bf2f(vw.z) * __builtin_amdgcn_rcpf(1.f + __expf(-(kt.z + __builtin_amdgcn_cvt_f32_fp8(qw, 2))));
    acc.w += bf2f(vw.w) * __builtin_amdgcn_rcpf(1.f + __expf(-(kt.w + __builtin_amdgcn_cvt_f32_fp8(qw, 3))));
  }
  if (valid){
    f32x4 o = { invT * acc.x + bf2f(sw.x), invT * acc.y + bf2f(sw.y),
                invT * acc.z + bf2f(sw.z), invT * acc.w + bf2f(sw.w) };
    *(f32x4*)&out[(size_t)node * DIM + l32 * 4] = o;
  }
}

// ---------------- launch -----------------------------------------------------
extern "C" void kernel_launch(void* const* d_in, const int* in_sizes, int n_in,
                              void* d_out, int out_size, void* d_ws, size_t ws_size,
                              hipStream_t stream){
  const float* x  = (const float*)d_in[0];
  const int*   ei = (const int*)d_in[1];
  const int*   et = (const int*)d_in[2];
  const float* Wk = (const float*)d_in[3];
  const float* bk = (const float*)d_in[4];
  const float* Wq = (const float*)d_in[5];
  const float* bq = (const float*)d_in[6];
  const float* Wv = (const float*)d_in[7];
  const float* bv = (const float*)d_in[8];
  const float* Ws = (const float*)d_in[9];
  const float* bb = (const float*)d_in[10];
  float* out = (float*)d_out;

  const int N = in_sizes[0] / DIM;
  const int E = in_sizes[2];
  const int T = in_sizes[3] / (DIM * DIM);
  const int NB = 3 * T + 1;
  const int ncol = NB * DIM;
  const int mtiles = (N + 127) / 128;
  const int rows = mtiles * 128;
  const int nscan = (N + 2047) / 2048;
  const int nsc = (E + 255) / 256;

  char* ws = (char*)d_ws;
  size_t off = 0;
  auto alloc = [&](size_t bytes) -> char* {
    char* p = ws + off;
    off = (off + bytes + 255) & ~(size_t)255;
    return p;
  };
  u16*   WcatT   = (u16*)alloc((size_t)ncol * DIM * 2);
  float* biascat = (float*)alloc((size_t)ncol * 4);
  char*  Y       = (char*)alloc((size_t)rows * ROWB);
  int*   cnt     = (int*)alloc((size_t)N * 4);
  int*   offs    = (int*)alloc((size_t)N * 4);
  int*   rank    = (int*)alloc((size_t)E * 4);
  int*   packed  = (int*)alloc((size_t)E * 4);
  int*   bsum    = (int*)alloc((size_t)nscan * 4);
  int*   boffs   = (int*)alloc((size_t)nscan * 4);
  (void)ws_size; (void)n_in; (void)out_size;

  const int* srcp = ei;
  const int* dstp = ei + E;

  hipMemsetAsync(cnt, 0, (size_t)N * 4, stream);
  int prep_total = E + NB * DIM * DIM;
  prep_kernel<<<(prep_total + 255) / 256, 256, 0, stream>>>(
      dstp, cnt, rank, Wk, bk, Wq, bq, Wv, bv, Ws, bb, WcatT, biascat, T, E);
  scan1_kernel<<<nscan, 256, 0, stream>>>(cnt, offs, bsum, N);
  scan2_kernel<<<1, 64, 0, stream>>>(bsum, boffs, nscan);
  gemm_scatter_kernel<<<nsc + NB * mtiles, 256, 0, stream>>>(
      x, WcatT, biascat, Y, srcp, dstp, et, offs, boffs, rank, packed,
      N, E, T, NB, mtiles, nsc);
  agg_kernel<<<(N + 7) / 8, 256, 0, stream>>>(Y, offs, boffs, packed, out, N, E, 1.0f / (float)T);
}

// Round 10
// 275.956 us; speedup vs baseline: 1.1069x; 1.1069x over previous
//
#include <hip/hip_runtime.h>

typedef unsigned short u16;
typedef unsigned int u32;
typedef __attribute__((ext_vector_type(8))) short bf16x8;
typedef __attribute__((ext_vector_type(4))) float f32x4;
typedef __attribute__((ext_vector_type(4))) u16 u16x4;
typedef __attribute__((ext_vector_type(2))) u32 u32x2;

#define DIM 128
// Y row (2304 B): per type t in 0..3 at t*384:
//   [0,128):   q fp8 (feat = byte offset)
//   [128,384): v bf16 (feat*2)
// 1536 + t*128: k fp8 ; 2048: s bf16
#define ROWB 2304
#define QV_SPAN 384
#define K_OFF 1536
#define S_OFF 2048
#define AS1C(p) ((const __attribute__((address_space(1))) void*)(p))
#define AS3P(p) ((__attribute__((address_space(3))) void*)(p))

__device__ __forceinline__ u32 f2bf(float f){
  u32 x = __float_as_uint(f);
  return (x + 0x7fffu + ((x >> 16) & 1u)) >> 16;
}
__device__ __forceinline__ float bf2f(u16 u){
  return __uint_as_float(((u32)u) << 16);
}

// ------- prep: hist + build W (bf16,transposed,concat) + cast x->bf16 --------
// Wcat tiles (13 x 128 cols): nt<4: Wq[nt]; 4..7: Wv; 8..11: Wk; 12: mean Ws.
__global__ __launch_bounds__(256) void prep_kernel(
    const float* __restrict__ x, u16* __restrict__ xb,
    const int* __restrict__ dst, int* __restrict__ cnt, int* __restrict__ rank,
    const float* __restrict__ Wk, const float* __restrict__ bk,
    const float* __restrict__ Wq, const float* __restrict__ bq,
    const float* __restrict__ Wv, const float* __restrict__ bv,
    const float* __restrict__ Ws, const float* __restrict__ bb,
    u16* __restrict__ WcatT, float* __restrict__ biascat,
    int T, int N, int E, int rows){
  int id = blockIdx.x * 256 + threadIdx.x;
  if (id < E){                     // histogram + rank
    rank[id] = atomicAdd(&cnt[dst[id]], 1);
    return;
  }
  id -= E;
  int total_w = (3 * T + 1) * DIM * DIM;
  if (id < total_w){               // weight build
    int kk = id & (DIM - 1);
    int c  = id >> 7;
    int nt = c >> 7;
    int j  = c & (DIM - 1);
    float wv, bvv;
    if (nt < T)        { wv = Wq[(nt*DIM + kk)*DIM + j];       bvv = bq[nt*DIM + j]; }
    else if (nt < 2*T) { wv = Wv[((nt-T)*DIM + kk)*DIM + j];   bvv = bv[(nt-T)*DIM + j]; }
    else if (nt < 3*T) { wv = Wk[((nt-2*T)*DIM + kk)*DIM + j]; bvv = bk[(nt-2*T)*DIM + j]; }
    else {
      float s = 0.f, sb = 0.f;
      for (int t = 0; t < T; ++t){ s += Ws[(t*DIM + kk)*DIM + j]; sb += bb[t*DIM + j]; }
      wv = s / (float)T; bvv = sb / (float)T;
    }
    WcatT[(size_t)c * DIM + kk] = (u16)f2bf(wv);
    if (kk == 0) biascat[c] = bvv;
    return;
  }
  id -= total_w;
  int total_cast = rows * (DIM / 4);
  if (id < total_cast){            // x -> bf16 (zero-padded rows)
    int el = id * 4;
    int node = el >> 7;
    u32x2 pk;
    if (node < N){
      f32x4 v = *(const f32x4*)(x + el);
      pk.x = f2bf(v.x) | (f2bf(v.y) << 16);
      pk.y = f2bf(v.z) | (f2bf(v.w) << 16);
    } else { pk.x = 0u; pk.y = 0u; }
    *(u32x2*)(xb + el) = pk;
  }
}

// per-2048-chunk exclusive scan (offs chunk-local; bsum = chunk totals)
__global__ __launch_bounds__(256) void scan1_kernel(const int* __restrict__ cnt,
                                                    int* __restrict__ offs,
                                                    int* __restrict__ bsum, int n){
  __shared__ int wsum[4];
  const int tid = threadIdx.x;
  const int lane = tid & 63, wave = tid >> 6;
  const int base = blockIdx.x * 2048 + tid * 8;
  int v[8]; int tot = 0;
#pragma unroll
  for (int j = 0; j < 8; ++j){
    int idx = base + j;
    int val = (idx < n) ? cnt[idx] : 0;
    v[j] = val; tot += val;
  }
  int incl = tot;
#pragma unroll
  for (int d = 1; d < 64; d <<= 1){
    int u = __shfl_up(incl, d, 64);
    if (lane >= d) incl += u;
  }
  if (lane == 63) wsum[wave] = incl;
  __syncthreads();
  int wbase = 0;
#pragma unroll
  for (int w = 0; w < 4; ++w) if (w < wave) wbase += wsum[w];
  int excl = wbase + incl - tot;
  if (tid == 255) bsum[blockIdx.x] = wbase + incl;
#pragma unroll
  for (int j = 0; j < 8; ++j){
    int idx = base + j;
    if (idx < n) offs[idx] = excl;
    excl += v[j];
  }
}

// exclusive scan of chunk sums (nb <= 64)
__global__ __launch_bounds__(64) void scan2_kernel(const int* __restrict__ bsum,
                                                   int* __restrict__ boffs, int nb){
  int lane = threadIdx.x;
  int v = (lane < nb) ? bsum[lane] : 0;
  int incl = v;
#pragma unroll
  for (int d = 1; d < 64; d <<= 1){
    int u = __shfl_up(incl, d, 64);
    if (lane >= d) incl += u;
  }
  if (lane < nb) boffs[lane] = incl - v;
}

// ---------------- fused scatter + GEMM ---------------------------------------
// Blocks [0, nsc): scatter packed[] (no atomics: offs+boffs+rank).
// Blocks [nsc, ...): GEMM Y = xb @ Wcat + bias, mixed fp8/bf16 epilogue.
// W-tile (32 KB) LDS, XOR swizzle, global_load_lds w16; x frags global->VGPR.
// XCD swizzle: groups of 8 blocks = 8 m-tiles; same-mt blocks share an XCD.
// D mapping (A=W^T frag, B=x frag): col(=node)=lane&15, row(=feat)=quad*4+reg.
__global__ __launch_bounds__(256, 4) void gemm_scatter_kernel(
    const u16* __restrict__ xb, const u16* __restrict__ WcatT,
    const float* __restrict__ biascat, char* __restrict__ Y,
    const int* __restrict__ src, const int* __restrict__ dst,
    const int* __restrict__ et, const int* __restrict__ offs,
    const int* __restrict__ boffs, const int* __restrict__ rank,
    int* __restrict__ packed,
    int N, int E, int T, int NB, int mtiles, int nsc){
  __shared__ u16 wt[DIM * DIM];   // 32 KB
  int bid = blockIdx.x;
  if (bid < nsc){
    int e = bid * 256 + threadIdx.x;
    if (e < E){
      int d = dst[e];
      int pos = offs[d] + boffs[d >> 11] + rank[e];
      packed[pos] = (src[e] << 2) | (et[e] & 3);
    }
    return;
  }
  bid -= nsc;
  int body = NB * (mtiles & ~7);
  int mt, nt;
  if (bid < body){
    int g = bid >> 3, r = bid & 7;
    int a = g / NB;
    mt = a * 8 + r;
    nt = g - a * NB;
  } else {
    int z = bid - body;
    mt = (mtiles & ~7) + z / NB;
    nt = z % NB;
  }
  const int m0 = mt * 128;
  const int n0 = nt * 128;
  const int tid  = threadIdx.x;
  const int wave = tid >> 6;
  const int lane = tid & 63;
  const int l15  = lane & 15;
  const int quad = lane >> 4;
  const int wrow = wave * 32;

  const u16* xrow0 = xb + (size_t)(m0 + wrow + l15) * DIM + quad * 8;
  const u16* xrow1 = xrow0 + 16 * DIM;

  // prefetch x fragments (independent of the LDS DMA)
  bf16x8 bfr[2][4];
#pragma unroll
  for (int ks = 0; ks < 4; ++ks){
    bfr[0][ks] = *(const bf16x8*)(xrow0 + ks * 32);
    bfr[1][ks] = *(const bf16x8*)(xrow1 + ks * 32);
  }

  // stage W tile, XOR swizzle: phys block p of row r holds logical p^(r&7)
#pragma unroll
  for (int it = 0; it < 8; ++it){
    int s  = it * 256 + tid;
    int r  = s >> 4;
    int p  = s & 15;
    int lb = p ^ (r & 7);
    int lbase = (it * 256 + wave * 64) * 8;
    __builtin_amdgcn_global_load_lds(AS1C(WcatT + (size_t)(n0 + r) * DIM + lb * 8),
                                     AS3P(wt + lbase), 16, 0, 0);
  }
  __syncthreads();

  f32x4 acc[2][8];
#pragma unroll
  for (int m = 0; m < 2; ++m)
#pragma unroll
    for (int f = 0; f < 8; ++f)
      acc[m][f] = (f32x4){0.f, 0.f, 0.f, 0.f};

#pragma unroll
  for (int ks = 0; ks < 4; ++ks){
    const int pb8 = (((ks * 4 + quad) ^ (l15 & 7)) * 8);
#pragma unroll
    for (int f = 0; f < 8; ++f){
      bf16x8 afr = *(const bf16x8*)&wt[(f * 16 + l15) * DIM + pb8];
      acc[0][f] = __builtin_amdgcn_mfma_f32_16x16x32_bf16(afr, bfr[0][ks], acc[0][f], 0, 0, 0);
      acc[1][f] = __builtin_amdgcn_mfma_f32_16x16x32_bf16(afr, bfr[1][ks], acc[1][f], 0, 0, 0);
    }
  }

  // epilogue by tile class: nt<T -> q fp8; [T,2T) -> v bf16; [2T,3T) -> k fp8;
  // nt=3T -> s bf16.
#pragma unroll
  for (int m = 0; m < 2; ++m){
    int node = m0 + wrow + m * 16 + l15;
    if (node >= N) continue;
    char* rb = Y + (size_t)node * ROWB;
#pragma unroll
    for (int f = 0; f < 8; ++f){
      int feat = f * 16 + quad * 4;
      f32x4 b4 = *(const f32x4*)&biascat[n0 + feat];
      f32x4 v  = acc[m][f];
      float a0 = v.x + b4.x, a1 = v.y + b4.y, a2 = v.z + b4.z, a3 = v.w + b4.w;
      bool is_q = (nt < T);
      bool is_k = (nt >= 2*T) && (nt < 3*T);
      if (is_q || is_k){                 // fp8 pack
        u32 w = __builtin_amdgcn_cvt_pk_fp8_f32(a0, a1, 0, false);
        w = __builtin_amdgcn_cvt_pk_fp8_f32(a2, a3, w, true);
        int boff = is_q ? (nt * QV_SPAN + feat) : (K_OFF + (nt - 2*T) * 128 + feat);
        *(u32*)(rb + boff) = w;
      } else {                           // bf16 pack (v or s)
        u32 lo = f2bf(a0) | (f2bf(a1) << 16);
        u32 hi = f2bf(a2) | (f2bf(a3) << 16);
        u32x2 pk = {lo, hi};
        int boff = (nt < 2*T) ? ((nt - T) * QV_SPAN + 128 + feat * 2)
                              : (S_OFF + feat * 2);
        *(u32x2*)(rb + boff) = pk;
      }
    }
  }
}

// ---------------- aggregate + epilogue: 2 nodes per wave (32 lanes each) -----
__global__ __launch_bounds__(256) void agg_kernel(const char* __restrict__ Y,
                                                  const int* __restrict__ offs,
                                                  const int* __restrict__ boffs,
                                                  const int* __restrict__ packed,
                                                  float* __restrict__ out,
                                                  int N, int E, float invT){
  const int wave = threadIdx.x >> 6;
  const int lane = threadIdx.x & 63;
  const int half = lane >> 5;
  const int l32  = lane & 31;
  const int node = blockIdx.x * 8 + wave * 2 + half;
  const bool valid = node < N;
  const int nc = valid ? node : N - 1;

  const char* yr = Y + (size_t)nc * ROWB;

  // k (fp8) per type -> f32x4; s (bf16)
  f32x4 kf[4];
#pragma unroll
  for (int t = 0; t < 4; ++t){
    u32 kw = *(const u32*)(yr + K_OFF + t * 128 + l32 * 4);
    kf[t] = (f32x4){ __builtin_amdgcn_cvt_f32_fp8(kw, 0), __builtin_amdgcn_cvt_f32_fp8(kw, 1),
                     __builtin_amdgcn_cvt_f32_fp8(kw, 2), __builtin_amdgcn_cvt_f32_fp8(kw, 3) };
  }
  u16x4 sw = *(const u16x4*)(yr + S_OFF + l32 * 8);

  int e0 = 0, e1 = 0;
  if (valid){
    e0 = offs[nc] + boffs[nc >> 11];
    e1 = (nc == N - 1) ? E : (offs[nc + 1] + boffs[(nc + 1) >> 11]);
  }

  f32x4 acc = {0.f, 0.f, 0.f, 0.f};
  int e = e0;
  for (; e + 8 <= e1; e += 8){
    int p[8];
#pragma unroll
    for (int j = 0; j < 8; ++j) p[j] = packed[e + j];
    u32 qw[8]; u16x4 vw[8];
#pragma unroll
    for (int j = 0; j < 8; ++j){
      const char* sb = Y + (size_t)(p[j] >> 2) * ROWB + (p[j] & 3) * QV_SPAN;
      qw[j] = *(const u32*)(sb + l32 * 4);
      vw[j] = *(const u16x4*)(sb + 128 + l32 * 8);
    }
#pragma unroll
    for (int j = 0; j < 8; ++j){
      int t = p[j] & 3;
      f32x4 kt = (t == 0) ? kf[0] : (t == 1) ? kf[1] : (t == 2) ? kf[2] : kf[3];
      acc.x += bf2f(vw[j].x) * __builtin_amdgcn_rcpf(1.f + __expf(-(kt.x + __builtin_amdgcn_cvt_f32_fp8(qw[j], 0))));
      acc.y += bf2f(vw[j].y) * __builtin_amdgcn_rcpf(1.f + __expf(-(kt.y + __builtin_amdgcn_cvt_f32_fp8(qw[j], 1))));
      acc.z += bf2f(vw[j].z) * __builtin_amdgcn_rcpf(1.f + __expf(-(kt.z + __builtin_amdgcn_cvt_f32_fp8(qw[j], 2))));
      acc.w += bf2f(vw[j].w) * __builtin_amdgcn_rcpf(1.f + __expf(-(kt.w + __builtin_amdgcn_cvt_f32_fp8(qw[j], 3))));
    }
  }
  for (; e < e1; ++e){
    int p = packed[e];
    int t = p & 3;
    const char* sb = Y + (size_t)(p >> 2) * ROWB + t * QV_SPAN;
    u32 qw = *(const u32*)(sb + l32 * 4);
    u16x4 vw = *(const u16x4*)(sb + 128 + l32 * 8);
    f32x4 kt = (t == 0) ? kf[0] : (t == 1) ? kf[1] : (t == 2) ? kf[2] : kf[3];
    acc.x += bf2f(vw.x) * __builtin_amdgcn_rcpf(1.f + __expf(-(kt.x + __builtin_amdgcn_cvt_f32_fp8(qw, 0))));
    acc.y += bf2f(vw.y) * __builtin_amdgcn_rcpf(1.f + __expf(-(kt.y + __builtin_amdgcn_cvt_f32_fp8(qw, 1))));
    acc.z += bf2f(vw.z) * __builtin_amdgcn_rcpf(1.f + __expf(-(kt.z + __builtin_amdgcn_cvt_f32_fp8(qw, 2))));
    acc.w += bf2f(vw.w) * __builtin_amdgcn_rcpf(1.f + __expf(-(kt.w + __builtin_amdgcn_cvt_f32_fp8(qw, 3))));
  }
  if (valid){
    f32x4 o = { invT * acc.x + bf2f(sw.x), invT * acc.y + bf2f(sw.y),
                invT * acc.z + bf2f(sw.z), invT * acc.w + bf2f(sw.w) };
    *(f32x4*)&out[(size_t)node * DIM + l32 * 4] = o;
  }
}

// ---------------- launch -----------------------------------------------------
extern "C" void kernel_launch(void* const* d_in, const int* in_sizes, int n_in,
                              void* d_out, int out_size, void* d_ws, size_t ws_size,
                              hipStream_t stream){
  const float* x  = (const float*)d_in[0];
  const int*   ei = (const int*)d_in[1];
  const int*   et = (const int*)d_in[2];
  const float* Wk = (const float*)d_in[3];
  const float* bk = (const float*)d_in[4];
  const float* Wq = (const float*)d_in[5];
  const float* bq = (const float*)d_in[6];
  const float* Wv = (const float*)d_in[7];
  const float* bv = (const float*)d_in[8];
  const float* Ws = (const float*)d_in[9];
  const float* bb = (const float*)d_in[10];
  float* out = (float*)d_out;

  const int N = in_sizes[0] / DIM;
  const int E = in_sizes[2];
  const int T = in_sizes[3] / (DIM * DIM);
  const int NB = 3 * T + 1;
  const int ncol = NB * DIM;
  const int mtiles = (N + 127) / 128;
  const int rows = mtiles * 128;
  const int nscan = (N + 2047) / 2048;
  const int nsc = (E + 255) / 256;

  char* ws = (char*)d_ws;
  size_t off = 0;
  auto alloc = [&](size_t bytes) -> char* {
    char* p = ws + off;
    off = (off + bytes + 255) & ~(size_t)255;
    return p;
  };
  u16*   xb      = (u16*)alloc((size_t)rows * DIM * 2);
  u16*   WcatT   = (u16*)alloc((size_t)ncol * DIM * 2);
  float* biascat = (float*)alloc((size_t)ncol * 4);
  char*  Y       = (char*)alloc((size_t)rows * ROWB);
  int*   cnt     = (int*)alloc((size_t)N * 4);
  int*   offs    = (int*)alloc((size_t)N * 4);
  int*   rank    = (int*)alloc((size_t)E * 4);
  int*   packed  = (int*)alloc((size_t)E * 4);
  int*   bsum    = (int*)alloc((size_t)nscan * 4);
  int*   boffs   = (int*)alloc((size_t)nscan * 4);
  (void)ws_size; (void)n_in; (void)out_size;

  const int* srcp = ei;
  const int* dstp = ei + E;

  hipMemsetAsync(cnt, 0, (size_t)N * 4, stream);
  int prep_total = E + NB * DIM * DIM + rows * (DIM / 4);
  prep_kernel<<<(prep_total + 255) / 256, 256, 0, stream>>>(
      x, xb, dstp, cnt, rank, Wk, bk, Wq, bq, Wv, bv, Ws, bb,
      WcatT, biascat, T, N, E, rows);
  scan1_kernel<<<nscan, 256, 0, stream>>>(cnt, offs, bsum, N);
  scan2_kernel<<<1, 64, 0, stream>>>(bsum, boffs, nscan);
  gemm_scatter_kernel<<<nsc + NB * mtiles, 256, 0, stream>>>(
      xb, WcatT, biascat, Y, srcp, dstp, et, offs, boffs, rank, packed,
      N, E, T, NB, mtiles, nsc);
  agg_kernel<<<(N + 7) / 8, 256, 0, stream>>>(Y, offs, boffs, packed, out, N, E, 1.0f / (float)T);
}